// Round 8
// baseline (29.468 us; speedup 1.0000x reference)
//
#include <hip/hip_runtime.h>

// EmbeddingBag(mean): B=1024, S=256, W=16, EMB=50, vocab=256.
// Round 8: FLAT predicated gather (no len-branches) for max memory ILP.
//  - Evidence: r5/r7 sorts (fewer DS instrs) lost; r4 (fewer DS instrs,
//    more VALU, branchy) lost badly; r6 prefetch won. => latency/ILP-bound,
//    not DS-throughput-bound. r6's VGPR=20 shows the nested if(len>k) tree
//    serialized the ds_reads (~2-3 in flight, ~60cy each).
//  - Fix: all 16 row indices via cndmask (sentinel row 256 = zeros), then
//    16 unconditional independent ds_read_b128; 4 accumulator chains.
//  - __launch_bounds__(1024,4): VGPR cap 128 so loads can stay in flight.
//    16 waves/CU (half occupancy) traded for per-wave ILP.
//  - Keeps r6: lenbuf in LDS, software-pipelined chars prefetch, contiguous
//    512-bag chunks, coalesced stores (float4 + float2 tail).

constexpr int EMB     = 50;
constexpr int RSTRIDE = 56;                  // dwords per padded row (224 B)
constexpr int ROWS    = 257;                 // 256 vocab + zero sentinel
constexpr int TBL_F   = ROWS * RSTRIDE;      // 14392 floats = 57568 B
constexpr int NBAGS   = 1024 * 256;          // 262144
constexpr int BLOCK   = 1024;
constexpr int TPB     = 13;                  // lanes per bag
constexpr int BPP     = BLOCK / TPB;         // 78 bags per pass
constexpr int CHUNK   = 512;                 // bags per block
constexpr int NPASS   = (CHUNK + BPP - 1) / BPP;  // 7 (tail pass: 44 bags)
constexpr int BLOCKS  = NBAGS / CHUNK;       // 512, exact

__global__ __launch_bounds__(BLOCK, 4) void embag_flat_kernel(
    const int*   __restrict__ chars,     // [NBAGS, W=16]
    const int*   __restrict__ lengths,   // [NBAGS]
    const float* __restrict__ table,     // [256, EMB]
    float*       __restrict__ out)       // [NBAGS, EMB]
{
    __shared__ float tbl[TBL_F];
    __shared__ int   lenbuf[CHUNK];
    __shared__ float invl[17];

    const int base = blockIdx.x * CHUNK;

    // Stage table (row 256 and cols 50..55 zero).
    for (int i = threadIdx.x; i < TBL_F; i += BLOCK) {
        const int r = i / RSTRIDE;
        const int c = i - r * RSTRIDE;
        tbl[i] = (r < 256 && c < EMB) ? table[r * EMB + c] : 0.0f;
    }
    if (threadIdx.x < CHUNK / 4)
        reinterpret_cast<int4*>(lenbuf)[threadIdx.x] =
            reinterpret_cast<const int4*>(lengths + base)[threadIdx.x];
    if (threadIdx.x < 17)
        invl[threadIdx.x] = threadIdx.x ? 1.0f / (float)threadIdx.x : 0.0f;
    __syncthreads();

    const int  lb     = threadIdx.x / TPB;             // bag slot in pass
    const int  t      = threadIdx.x - lb * TPB;        // 16B slot in row
    const bool active = (lb < BPP);
    const float* rowp = tbl + 4 * t;

    // Prologue: prefetch pass-0 chars.
    int idx = active ? lb : 0;
    const int4* cp0 = reinterpret_cast<const int4*>(chars + (size_t)(base + idx) * 16);
    int4 c0 = cp0[0], c1 = cp0[1], c2 = cp0[2], c3 = cp0[3];

    for (int p = 0; p < NPASS; ++p) {
        // Prefetch next pass's chars; retire under the 16 gathers below.
        const int idxn = (idx + BPP < CHUNK) ? idx + BPP : CHUNK - 1;
        const int4* cpn =
            reinterpret_cast<const int4*>(chars + (size_t)(base + idxn) * 16);
        const int4 n0 = cpn[0], n1 = cpn[1], n2 = cpn[2], n3 = cpn[3];

        if (active && idx < CHUNK) {
            const int len = lenbuf[idx];

            // All 16 row indices, predicated to the zero-sentinel row.
            int e[16] = {c0.x, c0.y, c0.z, c0.w,  c1.x, c1.y, c1.z, c1.w,
                         c2.x, c2.y, c2.z, c2.w,  c3.x, c3.y, c3.z, c3.w};
            #pragma unroll
            for (int w = 0; w < 16; ++w)
                e[w] = (w < len) ? e[w] : 256;

            // 16 independent ds_read_b128, 4 accumulator chains (len-16 chain
            // per component instead of 64).
            float4 s0 = make_float4(0.f,0.f,0.f,0.f), s1 = s0, s2 = s0, s3 = s0;
            #pragma unroll
            for (int w = 0; w < 16; w += 4) {
                const float4 v0 = *reinterpret_cast<const float4*>(rowp + e[w+0] * RSTRIDE);
                const float4 v1 = *reinterpret_cast<const float4*>(rowp + e[w+1] * RSTRIDE);
                const float4 v2 = *reinterpret_cast<const float4*>(rowp + e[w+2] * RSTRIDE);
                const float4 v3 = *reinterpret_cast<const float4*>(rowp + e[w+3] * RSTRIDE);
                s0.x += v0.x; s0.y += v0.y; s0.z += v0.z; s0.w += v0.w;
                s1.x += v1.x; s1.y += v1.y; s1.z += v1.z; s1.w += v1.w;
                s2.x += v2.x; s2.y += v2.y; s2.z += v2.z; s2.w += v2.w;
                s3.x += v3.x; s3.y += v3.y; s3.z += v3.z; s3.w += v3.w;
            }

            const float inv = invl[len];
            const float rx = ((s0.x + s1.x) + (s2.x + s3.x)) * inv;
            const float ry = ((s0.y + s1.y) + (s2.y + s3.y)) * inv;
            const float rz = ((s0.z + s1.z) + (s2.z + s3.z)) * inv;
            const float rw = ((s0.w + s1.w) + (s2.w + s3.w)) * inv;

            float* ob = out + (size_t)(base + idx) * EMB + 4u * (unsigned)t;
            if (t < 12)
                *reinterpret_cast<float4*>(ob) = make_float4(rx, ry, rz, rw);
            else
                *reinterpret_cast<float2*>(ob) = make_float2(rx, ry);  // elems 48,49
        }

        c0 = n0; c1 = n1; c2 = n2; c3 = n3;
        idx += BPP;
    }
}

extern "C" void kernel_launch(void* const* d_in, const int* in_sizes, int n_in,
                              void* d_out, int out_size, void* d_ws, size_t ws_size,
                              hipStream_t stream) {
    const int*   chars   = (const int*)d_in[0];   // [B,S,W] int32
    const int*   lengths = (const int*)d_in[1];   // [B,S]   int32
    const float* table   = (const float*)d_in[2]; // [256,50] f32
    float*       out     = (float*)d_out;         // [B,S,50] f32

    embag_flat_kernel<<<dim3(BLOCKS), dim3(BLOCK), 0, stream>>>(
        chars, lengths, table, out);
}